// Round 11
// baseline (436.782 us; speedup 1.0000x reference)
//
#include <hip/hip_runtime.h>

#define NF 64        // IN_F == HID_F == 64
#define BKSH 9       // bucket = dst >> 9 (512 nodes/bucket)
#define BKN 512      // nodes per bucket
#define SB 256       // superblocks (edge partitions)

typedef unsigned short u16;

__device__ __forceinline__ float bf2f(unsigned h) {
    return __uint_as_float(h << 16);
}
__device__ __forceinline__ u16 f2bf(float x) {   // round-to-nearest-even
    unsigned u = __float_as_uint(x);
    return (u16)((u + 0x7FFFu + ((u >> 16) & 1u)) >> 16);
}

// ============ CSR build: two-phase radix partition (round-10 proven) ============

__launch_bounds__(256)
__global__ void radix_count(const int* __restrict__ dst, int* __restrict__ hist,
                            int* __restrict__ bucket_total, int E, int epb, int nbuk) {
    __shared__ int bins[BKN];
    int tid = threadIdx.x, sb = blockIdx.x;
    for (int i = tid; i < nbuk; i += 256) bins[i] = 0;
    __syncthreads();
    int base = sb * epb;
    int end = min(base + epb, E);
    for (int e = base + tid; e < end; e += 256)
        atomicAdd(&bins[dst[e] >> BKSH], 1);
    __syncthreads();
    for (int i = tid; i < nbuk; i += 256) {
        int c = bins[i];
        hist[i * SB + sb] = c;
        if (c) atomicAdd(&bucket_total[i], c);
    }
}

__global__ void bucket_scan(const int* __restrict__ bucket_total, int* __restrict__ bucket_base,
                            int* __restrict__ rowptr, int nbuk, int E, int N) {
    __shared__ int s[256];
    int tid = threadIdx.x;
    int v = (tid < nbuk) ? bucket_total[tid] : 0;
    s[tid] = v; __syncthreads();
    for (int off = 1; off < 256; off <<= 1) {
        int t = (tid >= off) ? s[tid - off] : 0;
        __syncthreads();
        s[tid] += t;
        __syncthreads();
    }
    if (tid <= nbuk) bucket_base[tid] = (tid < nbuk) ? (s[tid] - v) : E;
    if (tid == 0) rowptr[N] = E;
}

__global__ void hist_scan(int* __restrict__ hist, const int* __restrict__ bucket_base) {
    __shared__ int s[256];
    int b = blockIdx.x, tid = threadIdx.x;
    int v = hist[b * SB + tid];
    s[tid] = v; __syncthreads();
    for (int off = 1; off < 256; off <<= 1) {
        int t = (tid >= off) ? s[tid - off] : 0;
        __syncthreads();
        s[tid] += t;
        __syncthreads();
    }
    hist[b * SB + tid] = bucket_base[b] + s[tid] - v;
}

__launch_bounds__(256)
__global__ void radix_scatter(const int* __restrict__ src, const int* __restrict__ dst,
                              const int* __restrict__ hist, int* __restrict__ tmp,
                              int E, int epb, int nbuk) {
    __shared__ int cur[BKN];
    int tid = threadIdx.x, sb = blockIdx.x;
    for (int i = tid; i < nbuk; i += 256) cur[i] = hist[i * SB + sb];
    __syncthreads();
    int base = sb * epb;
    int end = min(base + epb, E);
    for (int e = base + tid; e < end; e += 256) {
        int d = dst[e];
        int b = d >> BKSH;
        int pos = atomicAdd(&cur[b], 1);
        tmp[pos] = ((d & (BKN - 1)) << 17) | src[e];
    }
}

// one block per bucket: 512-bin LDS counting sort -> rowptr, dinv, rdinv, csr_src
__launch_bounds__(256)
__global__ void radix_build(const int* __restrict__ tmp, const int* __restrict__ bucket_base,
                            int* __restrict__ csr_src, int* __restrict__ rowptr,
                            float* __restrict__ dinv, float* __restrict__ rdinv, int N) {
    __shared__ int cnt[BKN], excl[BKN], cur[BKN];
    __shared__ int s[256];
    int b = blockIdx.x, tid = threadIdx.x;
    int beg = bucket_base[b], end = bucket_base[b + 1];
    cnt[tid] = 0; cnt[tid + 256] = 0;
    __syncthreads();
    for (int e = beg + tid; e < end; e += 256)
        atomicAdd(&cnt[(tmp[e] >> 17) & (BKN - 1)], 1);
    __syncthreads();
    int c0 = cnt[2 * tid], c1 = cnt[2 * tid + 1];
    int v = c0 + c1;
    s[tid] = v; __syncthreads();
    for (int off = 1; off < 256; off <<= 1) {
        int t = (tid >= off) ? s[tid - off] : 0;
        __syncthreads();
        s[tid] += t;
        __syncthreads();
    }
    int base2 = s[tid] - v;
    excl[2 * tid] = base2;
    excl[2 * tid + 1] = base2 + c0;
    cur[2 * tid] = 0; cur[2 * tid + 1] = 0;
    int node0 = b << BKSH;
    int n0 = node0 + 2 * tid, n1 = n0 + 1;
    if (n0 < N) {
        float m = fmaxf((float)c0, 1.0f);
        rowptr[n0] = beg + base2; dinv[n0] = rsqrtf(m); rdinv[n0] = sqrtf(m);
    }
    if (n1 < N) {
        float m = fmaxf((float)c1, 1.0f);
        rowptr[n1] = beg + base2 + c0; dinv[n1] = rsqrtf(m); rdinv[n1] = sqrtf(m);
    }
    __syncthreads();
    for (int e = beg + tid; e < end; e += 256) {
        int vv = tmp[e];
        int dlow = (vv >> 17) & (BKN - 1);
        int pos = excl[dlow] + atomicAdd(&cur[dlow], 1);
        csr_src[beg + pos] = vv & 0x1FFFF;
    }
}

// ============ prescale: Y = bf16(X * dinv[node]) ============
__global__ void prescale(const float* __restrict__ X, const float* __restrict__ dinv,
                         u16* __restrict__ Y, int total4) {   // total4 = N*16
    int i = blockIdx.x * blockDim.x + threadIdx.x;
    if (i < total4) {
        int node = i >> 4;
        float dn = dinv[node];
        float4 v = ((const float4*)X)[i];
        ushort4 y;
        y.x = f2bf(v.x * dn); y.y = f2bf(v.y * dn);
        y.z = f2bf(v.z * dn); y.w = f2bf(v.w * dn);
        ((ushort4*)Y)[i] = y;
    }
}

// ============ SpMM gathers: wave/node, 16 edges in flight, bf16 rows ============
#define SPMM_HEAD \
    int node = (blockIdx.x * blockDim.x + threadIdx.x) >> 6; \
    if (node >= n) return; \
    int lane = threadIdx.x & 63; \
    int g = lane >> 3; \
    int fl = (lane & 7) << 3; \
    int beg = rowptr[node], end = rowptr[node + 1]; \
    float acc[8], acc2[8]; \
    _Pragma("unroll") for (int j = 0; j < 8; ++j) { acc[j] = 0.f; acc2[j] = 0.f; } \
    int e0 = beg; \
    for (; e0 + 16 <= end; e0 += 16) { \
        int sA = csr_src[e0 + g]; \
        int sB = csr_src[e0 + 8 + g]; \
        uint4 uA = *(const uint4*)(Y + (size_t)sA * NF + fl); \
        uint4 uB = *(const uint4*)(Y + (size_t)sB * NF + fl); \
        acc[0] += bf2f(uA.x & 0xFFFFu); acc[1] += bf2f(uA.x >> 16); \
        acc[2] += bf2f(uA.y & 0xFFFFu); acc[3] += bf2f(uA.y >> 16); \
        acc[4] += bf2f(uA.z & 0xFFFFu); acc[5] += bf2f(uA.z >> 16); \
        acc[6] += bf2f(uA.w & 0xFFFFu); acc[7] += bf2f(uA.w >> 16); \
        acc2[0] += bf2f(uB.x & 0xFFFFu); acc2[1] += bf2f(uB.x >> 16); \
        acc2[2] += bf2f(uB.y & 0xFFFFu); acc2[3] += bf2f(uB.y >> 16); \
        acc2[4] += bf2f(uB.z & 0xFFFFu); acc2[5] += bf2f(uB.z >> 16); \
        acc2[6] += bf2f(uB.w & 0xFFFFu); acc2[7] += bf2f(uB.w >> 16); \
    } \
    for (; e0 < end; e0 += 8) { \
        int eg = e0 + g; \
        if (eg < end) { \
            int s = csr_src[eg]; \
            uint4 u = *(const uint4*)(Y + (size_t)s * NF + fl); \
            acc[0] += bf2f(u.x & 0xFFFFu); acc[1] += bf2f(u.x >> 16); \
            acc[2] += bf2f(u.y & 0xFFFFu); acc[3] += bf2f(u.y >> 16); \
            acc[4] += bf2f(u.z & 0xFFFFu); acc[5] += bf2f(u.z >> 16); \
            acc[6] += bf2f(u.w & 0xFFFFu); acc[7] += bf2f(u.w >> 16); \
        } \
    } \
    _Pragma("unroll") for (int j = 0; j < 8; ++j) acc[j] += acc2[j]; \
    _Pragma("unroll") for (int m = 8; m <= 32; m <<= 1) { \
        _Pragma("unroll") for (int j = 0; j < 8; ++j) acc[j] += __shfl_xor(acc[j], m, 64); \
    }

// mode 1: Yout = bf16(-acc * dinv^2)   (pre-scaled for the next gather)
__launch_bounds__(256)
__global__ void spmm_m1(const u16* __restrict__ Y, const int* __restrict__ rowptr,
                        const int* __restrict__ csr_src, const float* __restrict__ dinv,
                        u16* __restrict__ Yout, int n) {
    SPMM_HEAD
    if (g == 0) {
        float dn = dinv[node];
        float sc = -dn * dn;
        uint4 uy;
        uy.x = (unsigned)f2bf(acc[0] * sc) | ((unsigned)f2bf(acc[1] * sc) << 16);
        uy.y = (unsigned)f2bf(acc[2] * sc) | ((unsigned)f2bf(acc[3] * sc) << 16);
        uy.z = (unsigned)f2bf(acc[4] * sc) | ((unsigned)f2bf(acc[5] * sc) << 16);
        uy.w = (unsigned)f2bf(acc[6] * sc) | ((unsigned)f2bf(acc[7] * sc) << 16);
        *(uint4*)(Yout + (size_t)node * NF + fl) = uy;
    }
}

// mode 2: X2b = bf16(-2*acc*dinv - Xprev)   (plain bf16, gemm operand)
__launch_bounds__(256)
__global__ void spmm_m2(const u16* __restrict__ Y, const int* __restrict__ rowptr,
                        const int* __restrict__ csr_src, const float* __restrict__ dinv,
                        const float* __restrict__ Xprev, u16* __restrict__ X2b, int n) {
    SPMM_HEAD
    if (g == 0) {
        float dn = dinv[node];
        float4 a = *(const float4*)(Xprev + (size_t)node * NF + fl);
        float4 b = *(const float4*)(Xprev + (size_t)node * NF + fl + 4);
        float r0 = -2.f * acc[0] * dn - a.x, r1 = -2.f * acc[1] * dn - a.y;
        float r2 = -2.f * acc[2] * dn - a.z, r3 = -2.f * acc[3] * dn - a.w;
        float r4 = -2.f * acc[4] * dn - b.x, r5 = -2.f * acc[5] * dn - b.y;
        float r6 = -2.f * acc[6] * dn - b.z, r7 = -2.f * acc[7] * dn - b.w;
        uint4 uy;
        uy.x = (unsigned)f2bf(r0) | ((unsigned)f2bf(r1) << 16);
        uy.y = (unsigned)f2bf(r2) | ((unsigned)f2bf(r3) << 16);
        uy.z = (unsigned)f2bf(r4) | ((unsigned)f2bf(r5) << 16);
        uy.w = (unsigned)f2bf(r6) | ((unsigned)f2bf(r7) << 16);
        *(uint4*)(X2b + (size_t)node * NF + fl) = uy;
    }
}

// ============ GEMM v4: X0 fp32, X1 = Y1(bf16)*rdinv, X2 = X2b(bf16) ============
// 256 threads / 128 nodes; OUTF split across wave-pairs; LDS stride 36 (16B-aligned
// rows -> ds_read_b128 in the k-loop, 4 k-steps per LDS instruction).
template <int OUTF>
__launch_bounds__(256)
__global__ void gemm_cheb(const float* __restrict__ X0, const u16* __restrict__ Y1,
                          const u16* __restrict__ X2b, const float* __restrict__ rdinv,
                          const float* __restrict__ W, const float* __restrict__ bias,
                          float* __restrict__ out, const float* __restrict__ dinv,
                          u16* __restrict__ Yout, int n, int do_relu) {
    constexpr int HALF = OUTF / 2;     // 32 or 16
    constexpr int EST = HALF + 1;
    __shared__ float xs[128 * 36];
    const int tid = threadIdx.x;
    const int node0 = blockIdx.x * 128;
    const int ln = tid & 127;
    const int ho_u = __builtin_amdgcn_readfirstlane(tid >> 7);

    float acc[HALF];
#pragma unroll
    for (int j = 0; j < HALF; ++j) acc[j] = bias[ho_u * HALF + j];

#pragma unroll 1
    for (int p = 0; p < 3; ++p) {
#pragma unroll 1
        for (int h = 0; h < 2; ++h) {
            if (p == 0) {
                // fp32 operand: 1024 float4 / 256 threads = 4 iters
#pragma unroll
                for (int it = 0; it < 4; ++it) {
                    int idx4 = it * 256 + tid;
                    int ln2 = idx4 >> 3;
                    int k4 = (idx4 & 7) * 4;
                    float4 v = make_float4(0.f, 0.f, 0.f, 0.f);
                    int gnode = node0 + ln2;
                    if (gnode < n) v = *(const float4*)&X0[(size_t)gnode * 64 + h * 32 + k4];
                    *(float4*)&xs[ln2 * 36 + k4] = v;
                }
            } else {
                // bf16 operand: 512 uint4 / 256 threads = 2 iters (8 vals each)
                const u16* __restrict__ Xb = (p == 1) ? Y1 : X2b;
#pragma unroll
                for (int it = 0; it < 2; ++it) {
                    int idx8 = it * 256 + tid;
                    int ln2 = idx8 >> 2;
                    int k8 = (idx8 & 3) * 8;
                    int gnode = node0 + ln2;
                    float4 v0 = make_float4(0.f, 0.f, 0.f, 0.f);
                    float4 v1 = make_float4(0.f, 0.f, 0.f, 0.f);
                    if (gnode < n) {
                        uint4 u = *(const uint4*)&Xb[(size_t)gnode * 64 + h * 32 + k8];
                        float r = (p == 1) ? rdinv[gnode] : 1.0f;
                        v0.x = bf2f(u.x & 0xFFFFu) * r; v0.y = bf2f(u.x >> 16) * r;
                        v0.z = bf2f(u.y & 0xFFFFu) * r; v0.w = bf2f(u.y >> 16) * r;
                        v1.x = bf2f(u.z & 0xFFFFu) * r; v1.y = bf2f(u.z >> 16) * r;
                        v1.z = bf2f(u.w & 0xFFFFu) * r; v1.w = bf2f(u.w >> 16) * r;
                    }
                    *(float4*)&xs[ln2 * 36 + k8] = v0;
                    *(float4*)&xs[ln2 * 36 + k8 + 4] = v1;
                }
            }
            __syncthreads();

            const float* __restrict__ Wp =
                W + (size_t)p * 64 * OUTF + (size_t)h * 32 * OUTF + ho_u * HALF;
#pragma unroll 2
            for (int k4i = 0; k4i < 32; k4i += 4) {
                float4 xv = *(const float4*)&xs[ln * 36 + k4i];
#pragma unroll
                for (int kk = 0; kk < 4; ++kk) {
                    float x = (kk == 0) ? xv.x : (kk == 1) ? xv.y : (kk == 2) ? xv.z : xv.w;
#pragma unroll
                    for (int j = 0; j < HALF; ++j)
                        acc[j] += x * Wp[(k4i + kk) * OUTF + j];
                }
            }
            __syncthreads();
        }
    }

    // ---- epilogue: two phases, compile-time indices, coalesced stores ----
#pragma unroll 1
    for (int hp = 0; hp < 2; ++hp) {
        if (ho_u == hp) {
#pragma unroll
            for (int j = 0; j < HALF; ++j) {
                float v = acc[j];
                if (do_relu) v = fmaxf(v, 0.f);
                xs[ln * EST + j] = v;
            }
        }
        __syncthreads();
        constexpr int NIT = (128 * HALF / 4) / 256;
#pragma unroll
        for (int it = 0; it < NIT; ++it) {
            int idx4 = it * 256 + tid;
            int ln2 = idx4 / (HALF / 4);
            int k4 = (idx4 % (HALF / 4)) * 4;
            int gnode = node0 + ln2;
            if (gnode < n) {
                const float* s = &xs[ln2 * EST + k4];
                float4 v = make_float4(s[0], s[1], s[2], s[3]);
                *(float4*)&out[(size_t)gnode * OUTF + hp * HALF + k4] = v;
                if (OUTF == 64 && Yout) {
                    float dn = dinv[gnode];
                    ushort4 y;
                    y.x = f2bf(v.x * dn); y.y = f2bf(v.y * dn);
                    y.z = f2bf(v.z * dn); y.w = f2bf(v.w * dn);
                    *(ushort4*)&Yout[(size_t)gnode * OUTF + hp * HALF + k4] = y;
                }
            }
        }
        __syncthreads();
    }
}

extern "C" void kernel_launch(void* const* d_in, const int* in_sizes, int n_in,
                              void* d_out, int out_size, void* d_ws, size_t ws_size,
                              hipStream_t stream) {
    const float* feat = (const float*)d_in[0];
    const int*   src  = (const int*)d_in[1];
    const int*   dst  = (const int*)d_in[2];
    const float* W1   = (const float*)d_in[3];
    const float* b1   = (const float*)d_in[4];
    const float* W2   = (const float*)d_in[5];
    const float* b2   = (const float*)d_in[6];
    float* out = (float*)d_out;

    const int N = in_sizes[0] / NF;   // 100000
    const int E = in_sizes[1];        // 1600000
    const size_t NFtot = (size_t)N * NF;
    const int nbuk = (N + BKN - 1) >> BKSH;   // 196
    const int epb = (E + SB - 1) / SB;        // 6250

    // workspace layout (16B-aligned chunks)
    char* p = (char*)d_ws;
    int* hist         = (int*)p;   p += (size_t)BKN * SB * 4;
    int* bucket_total = (int*)p;   p += (BKN + 16) * 4;
    int* bucket_base  = (int*)p;   p += (BKN + 16) * 4;
    int* rowptr       = (int*)p;   p += ((size_t)N + 16) * 4;
    int* csr_src      = (int*)p;   p += (size_t)E * 4;
    float* dinv       = (float*)p; p += ((size_t)N + 16) * 4;
    float* rdinv      = (float*)p; p += ((size_t)N + 16) * 4;
    float* H          = (float*)p; p += NFtot * 4;
    u16* Ya           = (u16*)p;   p += NFtot * 2;   // Y0, later YH (12.8 MB)
    u16* Yb           = (u16*)p;   p += NFtot * 2;   // Y1 (both layers)
    u16* X2b          = (u16*)p;   p += NFtot * 2;   // bf16 X2 (both layers)
    int* tmp = (int*)Ya;           // 6.4 MB alias; consumed before prescale writes Ya

    const int TB = 256;
    dim3 blk(TB);
    dim3 gWave(((size_t)N * 64 + TB - 1) / TB);
    dim3 gPre(((size_t)N * 16 + TB - 1) / TB);
    dim3 gGemm((N + 127) / 128);

    // ---- CSR build (radix partition) ----
    hipMemsetAsync(bucket_total, 0, (size_t)(BKN + 1) * sizeof(int), stream);
    radix_count<<<dim3(SB), blk, 0, stream>>>(dst, hist, bucket_total, E, epb, nbuk);
    bucket_scan<<<1, blk, 0, stream>>>(bucket_total, bucket_base, rowptr, nbuk, E, N);
    hist_scan<<<dim3(nbuk), blk, 0, stream>>>(hist, bucket_base);
    radix_scatter<<<dim3(SB), blk, 0, stream>>>(src, dst, hist, tmp, E, epb, nbuk);
    radix_build<<<dim3(nbuk), blk, 0, stream>>>(tmp, bucket_base, csr_src, rowptr,
                                                dinv, rdinv, N);

    // ---- layer 1 ----
    prescale<<<gPre, blk, 0, stream>>>(feat, dinv, Ya, (int)(N * 16));
    spmm_m1<<<gWave, blk, 0, stream>>>(Ya, rowptr, csr_src, dinv, Yb, N);
    spmm_m2<<<gWave, blk, 0, stream>>>(Yb, rowptr, csr_src, dinv, feat, X2b, N);
    gemm_cheb<64><<<gGemm, blk, 0, stream>>>(feat, Yb, X2b, rdinv, W1, b1, H,
                                             dinv, Ya, N, 1);

    // ---- layer 2 ----
    spmm_m1<<<gWave, blk, 0, stream>>>(Ya, rowptr, csr_src, dinv, Yb, N);
    spmm_m2<<<gWave, blk, 0, stream>>>(Yb, rowptr, csr_src, dinv, H, X2b, N);
    gemm_cheb<32><<<gGemm, blk, 0, stream>>>(H, Yb, X2b, rdinv, W2, b2, out,
                                             dinv, nullptr, N, 0);
}

// Round 12
// 434.983 us; speedup vs baseline: 1.0041x; 1.0041x over previous
//
#include <hip/hip_runtime.h>

#define NF 64        // IN_F == HID_F == 64
#define BKSH 9       // bucket = dst >> 9 (512 nodes/bucket)
#define BKN 512      // nodes per bucket
#define SB 256       // superblocks (edge partitions)

typedef unsigned short u16;

__device__ __forceinline__ float bf2f(unsigned h) {
    return __uint_as_float(h << 16);
}
__device__ __forceinline__ u16 f2bf(float x) {   // round-to-nearest-even
    unsigned u = __float_as_uint(x);
    return (u16)((u + 0x7FFFu + ((u >> 16) & 1u)) >> 16);
}

// ============ CSR build: two-phase radix partition (round-10 proven) ============

__launch_bounds__(256)
__global__ void radix_count(const int* __restrict__ dst, int* __restrict__ hist,
                            int* __restrict__ bucket_total, int E, int epb, int nbuk) {
    __shared__ int bins[BKN];
    int tid = threadIdx.x, sb = blockIdx.x;
    for (int i = tid; i < nbuk; i += 256) bins[i] = 0;
    __syncthreads();
    int base = sb * epb;
    int end = min(base + epb, E);
    for (int e = base + tid; e < end; e += 256)
        atomicAdd(&bins[dst[e] >> BKSH], 1);
    __syncthreads();
    for (int i = tid; i < nbuk; i += 256) {
        int c = bins[i];
        hist[i * SB + sb] = c;
        if (c) atomicAdd(&bucket_total[i], c);
    }
}

__global__ void bucket_scan(const int* __restrict__ bucket_total, int* __restrict__ bucket_base,
                            int* __restrict__ rowptr, int nbuk, int E, int N) {
    __shared__ int s[256];
    int tid = threadIdx.x;
    int v = (tid < nbuk) ? bucket_total[tid] : 0;
    s[tid] = v; __syncthreads();
    for (int off = 1; off < 256; off <<= 1) {
        int t = (tid >= off) ? s[tid - off] : 0;
        __syncthreads();
        s[tid] += t;
        __syncthreads();
    }
    if (tid <= nbuk) bucket_base[tid] = (tid < nbuk) ? (s[tid] - v) : E;
    if (tid == 0) rowptr[N] = E;
}

__global__ void hist_scan(int* __restrict__ hist, const int* __restrict__ bucket_base) {
    __shared__ int s[256];
    int b = blockIdx.x, tid = threadIdx.x;
    int v = hist[b * SB + tid];
    s[tid] = v; __syncthreads();
    for (int off = 1; off < 256; off <<= 1) {
        int t = (tid >= off) ? s[tid - off] : 0;
        __syncthreads();
        s[tid] += t;
        __syncthreads();
    }
    hist[b * SB + tid] = bucket_base[b] + s[tid] - v;
}

__launch_bounds__(256)
__global__ void radix_scatter(const int* __restrict__ src, const int* __restrict__ dst,
                              const int* __restrict__ hist, int* __restrict__ tmp,
                              int E, int epb, int nbuk) {
    __shared__ int cur[BKN];
    int tid = threadIdx.x, sb = blockIdx.x;
    for (int i = tid; i < nbuk; i += 256) cur[i] = hist[i * SB + sb];
    __syncthreads();
    int base = sb * epb;
    int end = min(base + epb, E);
    for (int e = base + tid; e < end; e += 256) {
        int d = dst[e];
        int b = d >> BKSH;
        int pos = atomicAdd(&cur[b], 1);
        tmp[pos] = ((d & (BKN - 1)) << 17) | src[e];
    }
}

__launch_bounds__(256)
__global__ void radix_build(const int* __restrict__ tmp, const int* __restrict__ bucket_base,
                            int* __restrict__ csr_src, int* __restrict__ rowptr,
                            float* __restrict__ dinv, float* __restrict__ rdinv, int N) {
    __shared__ int cnt[BKN], excl[BKN], cur[BKN];
    __shared__ int s[256];
    int b = blockIdx.x, tid = threadIdx.x;
    int beg = bucket_base[b], end = bucket_base[b + 1];
    cnt[tid] = 0; cnt[tid + 256] = 0;
    __syncthreads();
    for (int e = beg + tid; e < end; e += 256)
        atomicAdd(&cnt[(tmp[e] >> 17) & (BKN - 1)], 1);
    __syncthreads();
    int c0 = cnt[2 * tid], c1 = cnt[2 * tid + 1];
    int v = c0 + c1;
    s[tid] = v; __syncthreads();
    for (int off = 1; off < 256; off <<= 1) {
        int t = (tid >= off) ? s[tid - off] : 0;
        __syncthreads();
        s[tid] += t;
        __syncthreads();
    }
    int base2 = s[tid] - v;
    excl[2 * tid] = base2;
    excl[2 * tid + 1] = base2 + c0;
    cur[2 * tid] = 0; cur[2 * tid + 1] = 0;
    int node0 = b << BKSH;
    int n0 = node0 + 2 * tid, n1 = n0 + 1;
    if (n0 < N) {
        float m = fmaxf((float)c0, 1.0f);
        rowptr[n0] = beg + base2; dinv[n0] = rsqrtf(m); rdinv[n0] = sqrtf(m);
    }
    if (n1 < N) {
        float m = fmaxf((float)c1, 1.0f);
        rowptr[n1] = beg + base2 + c0; dinv[n1] = rsqrtf(m); rdinv[n1] = sqrtf(m);
    }
    __syncthreads();
    for (int e = beg + tid; e < end; e += 256) {
        int vv = tmp[e];
        int dlow = (vv >> 17) & (BKN - 1);
        int pos = excl[dlow] + atomicAdd(&cur[dlow], 1);
        csr_src[beg + pos] = vv & 0x1FFFF;
    }
}

// ============ prescale: Y = bf16(X * dinv[node]) ============
__global__ void prescale(const float* __restrict__ X, const float* __restrict__ dinv,
                         u16* __restrict__ Y, int total4) {   // total4 = N*16
    int i = blockIdx.x * blockDim.x + threadIdx.x;
    if (i < total4) {
        int node = i >> 4;
        float dn = dinv[node];
        float4 v = ((const float4*)X)[i];
        ushort4 y;
        y.x = f2bf(v.x * dn); y.y = f2bf(v.y * dn);
        y.z = f2bf(v.z * dn); y.w = f2bf(v.w * dn);
        ((ushort4*)Y)[i] = y;
    }
}

// ============ SpMM gathers: wave/node, 16 edges in flight, bf16 rows ============
#define SPMM_HEAD \
    int node = (blockIdx.x * blockDim.x + threadIdx.x) >> 6; \
    if (node >= n) return; \
    int lane = threadIdx.x & 63; \
    int g = lane >> 3; \
    int fl = (lane & 7) << 3; \
    int beg = rowptr[node], end = rowptr[node + 1]; \
    float acc[8], acc2[8]; \
    _Pragma("unroll") for (int j = 0; j < 8; ++j) { acc[j] = 0.f; acc2[j] = 0.f; } \
    int e0 = beg; \
    for (; e0 + 16 <= end; e0 += 16) { \
        int sA = csr_src[e0 + g]; \
        int sB = csr_src[e0 + 8 + g]; \
        uint4 uA = *(const uint4*)(Y + (size_t)sA * NF + fl); \
        uint4 uB = *(const uint4*)(Y + (size_t)sB * NF + fl); \
        acc[0] += bf2f(uA.x & 0xFFFFu); acc[1] += bf2f(uA.x >> 16); \
        acc[2] += bf2f(uA.y & 0xFFFFu); acc[3] += bf2f(uA.y >> 16); \
        acc[4] += bf2f(uA.z & 0xFFFFu); acc[5] += bf2f(uA.z >> 16); \
        acc[6] += bf2f(uA.w & 0xFFFFu); acc[7] += bf2f(uA.w >> 16); \
        acc2[0] += bf2f(uB.x & 0xFFFFu); acc2[1] += bf2f(uB.x >> 16); \
        acc2[2] += bf2f(uB.y & 0xFFFFu); acc2[3] += bf2f(uB.y >> 16); \
        acc2[4] += bf2f(uB.z & 0xFFFFu); acc2[5] += bf2f(uB.z >> 16); \
        acc2[6] += bf2f(uB.w & 0xFFFFu); acc2[7] += bf2f(uB.w >> 16); \
    } \
    for (; e0 < end; e0 += 8) { \
        int eg = e0 + g; \
        if (eg < end) { \
            int s = csr_src[eg]; \
            uint4 u = *(const uint4*)(Y + (size_t)s * NF + fl); \
            acc[0] += bf2f(u.x & 0xFFFFu); acc[1] += bf2f(u.x >> 16); \
            acc[2] += bf2f(u.y & 0xFFFFu); acc[3] += bf2f(u.y >> 16); \
            acc[4] += bf2f(u.z & 0xFFFFu); acc[5] += bf2f(u.z >> 16); \
            acc[6] += bf2f(u.w & 0xFFFFu); acc[7] += bf2f(u.w >> 16); \
        } \
    } \
    _Pragma("unroll") for (int j = 0; j < 8; ++j) acc[j] += acc2[j]; \
    _Pragma("unroll") for (int m = 8; m <= 32; m <<= 1) { \
        _Pragma("unroll") for (int j = 0; j < 8; ++j) acc[j] += __shfl_xor(acc[j], m, 64); \
    }

// mode 1: Yout = bf16(-acc * dinv^2)   (pre-scaled for the next gather)
__launch_bounds__(256)
__global__ void spmm_m1(const u16* __restrict__ Y, const int* __restrict__ rowptr,
                        const int* __restrict__ csr_src, const float* __restrict__ dinv,
                        u16* __restrict__ Yout, int n) {
    SPMM_HEAD
    if (g == 0) {
        float dn = dinv[node];
        float sc = -dn * dn;
        uint4 uy;
        uy.x = (unsigned)f2bf(acc[0] * sc) | ((unsigned)f2bf(acc[1] * sc) << 16);
        uy.y = (unsigned)f2bf(acc[2] * sc) | ((unsigned)f2bf(acc[3] * sc) << 16);
        uy.z = (unsigned)f2bf(acc[4] * sc) | ((unsigned)f2bf(acc[5] * sc) << 16);
        uy.w = (unsigned)f2bf(acc[6] * sc) | ((unsigned)f2bf(acc[7] * sc) << 16);
        *(uint4*)(Yout + (size_t)node * NF + fl) = uy;
    }
}

// mode 2: X2b = bf16(-2*acc*dinv - Xprev)   (plain bf16, gemm operand)
__launch_bounds__(256)
__global__ void spmm_m2(const u16* __restrict__ Y, const int* __restrict__ rowptr,
                        const int* __restrict__ csr_src, const float* __restrict__ dinv,
                        const float* __restrict__ Xprev, u16* __restrict__ X2b, int n) {
    SPMM_HEAD
    if (g == 0) {
        float dn = dinv[node];
        float4 a = *(const float4*)(Xprev + (size_t)node * NF + fl);
        float4 b = *(const float4*)(Xprev + (size_t)node * NF + fl + 4);
        float r0 = -2.f * acc[0] * dn - a.x, r1 = -2.f * acc[1] * dn - a.y;
        float r2 = -2.f * acc[2] * dn - a.z, r3 = -2.f * acc[3] * dn - a.w;
        float r4 = -2.f * acc[4] * dn - b.x, r5 = -2.f * acc[5] * dn - b.y;
        float r6 = -2.f * acc[6] * dn - b.z, r7 = -2.f * acc[7] * dn - b.w;
        uint4 uy;
        uy.x = (unsigned)f2bf(r0) | ((unsigned)f2bf(r1) << 16);
        uy.y = (unsigned)f2bf(r2) | ((unsigned)f2bf(r3) << 16);
        uy.z = (unsigned)f2bf(r4) | ((unsigned)f2bf(r5) << 16);
        uy.w = (unsigned)f2bf(r6) | ((unsigned)f2bf(r7) << 16);
        *(uint4*)(X2b + (size_t)node * NF + fl) = uy;
    }
}

// ============ GEMM v5: 64 nodes/block, 256 threads, OUTF quartered across waves ====
// Grid = 1563 blocks (~6/CU, ~24 waves/CU). LDS stride 33 (conflict-free scalar
// reads, lane+k mod 32 = 2-way max). acc[OUTF/4]; W offsets wave-uniform -> s_load.
template <int OUTF>
__launch_bounds__(256)
__global__ void gemm_cheb(const float* __restrict__ X0, const u16* __restrict__ Y1,
                          const u16* __restrict__ X2b, const float* __restrict__ rdinv,
                          const float* __restrict__ W, const float* __restrict__ bias,
                          float* __restrict__ out, const float* __restrict__ dinv,
                          u16* __restrict__ Yout, int n, int do_relu) {
    constexpr int QTR = OUTF / 4;      // 16 or 8
    constexpr int EST = QTR + 1;       // 17 or 9
    __shared__ float xs[64 * 33];
    const int tid = threadIdx.x;
    const int node0 = blockIdx.x * 64;
    const int ln = tid & 63;
    const int ho_u = __builtin_amdgcn_readfirstlane(tid >> 6);  // wave-uniform quarter

    float acc[QTR];
#pragma unroll
    for (int j = 0; j < QTR; ++j) acc[j] = bias[ho_u * QTR + j];

#pragma unroll 1
    for (int p = 0; p < 3; ++p) {
#pragma unroll 1
        for (int h = 0; h < 2; ++h) {
            if (p == 0) {
                // fp32 operand: 64 rows x 32 floats = 512 float4 / 256 thr = 2 iters
#pragma unroll
                for (int it = 0; it < 2; ++it) {
                    int idx4 = it * 256 + tid;
                    int ln2 = idx4 >> 3;
                    int k4 = (idx4 & 7) * 4;
                    float4 v = make_float4(0.f, 0.f, 0.f, 0.f);
                    int gnode = node0 + ln2;
                    if (gnode < n) v = *(const float4*)&X0[(size_t)gnode * 64 + h * 32 + k4];
                    float* s = &xs[ln2 * 33 + k4];
                    s[0] = v.x; s[1] = v.y; s[2] = v.z; s[3] = v.w;
                }
            } else {
                // bf16 operand: 64 rows x 32 bf16 = 256 uint4 / 256 thr = 1 iter
                const u16* __restrict__ Xb = (p == 1) ? Y1 : X2b;
                int ln2 = tid >> 2;
                int k8 = (tid & 3) * 8;
                int gnode = node0 + ln2;
                float4 v0 = make_float4(0.f, 0.f, 0.f, 0.f);
                float4 v1 = make_float4(0.f, 0.f, 0.f, 0.f);
                if (gnode < n) {
                    uint4 u = *(const uint4*)&Xb[(size_t)gnode * 64 + h * 32 + k8];
                    float r = (p == 1) ? rdinv[gnode] : 1.0f;
                    v0.x = bf2f(u.x & 0xFFFFu) * r; v0.y = bf2f(u.x >> 16) * r;
                    v0.z = bf2f(u.y & 0xFFFFu) * r; v0.w = bf2f(u.y >> 16) * r;
                    v1.x = bf2f(u.z & 0xFFFFu) * r; v1.y = bf2f(u.z >> 16) * r;
                    v1.z = bf2f(u.w & 0xFFFFu) * r; v1.w = bf2f(u.w >> 16) * r;
                }
                float* s = &xs[ln2 * 33 + k8];
                s[0] = v0.x; s[1] = v0.y; s[2] = v0.z; s[3] = v0.w;
                s[4] = v1.x; s[5] = v1.y; s[6] = v1.z; s[7] = v1.w;
            }
            __syncthreads();

            const float* __restrict__ Wp =
                W + (size_t)p * 64 * OUTF + (size_t)h * 32 * OUTF + ho_u * QTR;
            for (int k = 0; k < 32; ++k) {
                float x = xs[ln * 33 + k];
#pragma unroll
                for (int j = 0; j < QTR; ++j)
                    acc[j] += x * Wp[k * OUTF + j];
            }
            __syncthreads();
        }
    }

    // ---- epilogue: 4 phases (one per wave's quarter), compile-time indices ----
#pragma unroll 1
    for (int hp = 0; hp < 4; ++hp) {
        if (ho_u == hp) {
#pragma unroll
            for (int j = 0; j < QTR; ++j) {
                float v = acc[j];
                if (do_relu) v = fmaxf(v, 0.f);
                xs[ln * EST + j] = v;
            }
        }
        __syncthreads();
        // copy 64 rows x QTR floats, coalesced
        constexpr int TOT4 = 64 * QTR / 4;   // 256 (OUTF=64) or 128 (OUTF=32)
        int idx4 = tid;
        if (idx4 < TOT4) {
            int ln2 = idx4 / (QTR / 4);
            int k4 = (idx4 % (QTR / 4)) * 4;
            int gnode = node0 + ln2;
            if (gnode < n) {
                const float* s = &xs[ln2 * EST + k4];
                float4 v = make_float4(s[0], s[1], s[2], s[3]);
                *(float4*)&out[(size_t)gnode * OUTF + hp * QTR + k4] = v;
                if (OUTF == 64 && Yout) {
                    float dn = dinv[gnode];
                    ushort4 y;
                    y.x = f2bf(v.x * dn); y.y = f2bf(v.y * dn);
                    y.z = f2bf(v.z * dn); y.w = f2bf(v.w * dn);
                    *(ushort4*)&Yout[(size_t)gnode * OUTF + hp * QTR + k4] = y;
                }
            }
        }
        __syncthreads();
    }
}

extern "C" void kernel_launch(void* const* d_in, const int* in_sizes, int n_in,
                              void* d_out, int out_size, void* d_ws, size_t ws_size,
                              hipStream_t stream) {
    const float* feat = (const float*)d_in[0];
    const int*   src  = (const int*)d_in[1];
    const int*   dst  = (const int*)d_in[2];
    const float* W1   = (const float*)d_in[3];
    const float* b1   = (const float*)d_in[4];
    const float* W2   = (const float*)d_in[5];
    const float* b2   = (const float*)d_in[6];
    float* out = (float*)d_out;

    const int N = in_sizes[0] / NF;   // 100000
    const int E = in_sizes[1];        // 1600000
    const size_t NFtot = (size_t)N * NF;
    const int nbuk = (N + BKN - 1) >> BKSH;   // 196
    const int epb = (E + SB - 1) / SB;        // 6250

    // workspace layout (16B-aligned chunks)
    char* p = (char*)d_ws;
    int* hist         = (int*)p;   p += (size_t)BKN * SB * 4;
    int* bucket_total = (int*)p;   p += (BKN + 16) * 4;
    int* bucket_base  = (int*)p;   p += (BKN + 16) * 4;
    int* rowptr       = (int*)p;   p += ((size_t)N + 16) * 4;
    int* csr_src      = (int*)p;   p += (size_t)E * 4;
    float* dinv       = (float*)p; p += ((size_t)N + 16) * 4;
    float* rdinv      = (float*)p; p += ((size_t)N + 16) * 4;
    float* H          = (float*)p; p += NFtot * 4;
    u16* Ya           = (u16*)p;   p += NFtot * 2;   // Y0, later YH
    u16* Yb           = (u16*)p;   p += NFtot * 2;   // Y1 (both layers)
    u16* X2b          = (u16*)p;   p += NFtot * 2;   // bf16 X2 (both layers)
    int* tmp = (int*)Ya;           // alias; consumed before prescale writes Ya

    const int TB = 256;
    dim3 blk(TB);
    dim3 gWave(((size_t)N * 64 + TB - 1) / TB);
    dim3 gPre(((size_t)N * 16 + TB - 1) / TB);
    dim3 gGemm((N + 63) / 64);

    // ---- CSR build (radix partition) ----
    hipMemsetAsync(bucket_total, 0, (size_t)(BKN + 1) * sizeof(int), stream);
    radix_count<<<dim3(SB), blk, 0, stream>>>(dst, hist, bucket_total, E, epb, nbuk);
    bucket_scan<<<1, blk, 0, stream>>>(bucket_total, bucket_base, rowptr, nbuk, E, N);
    hist_scan<<<dim3(nbuk), blk, 0, stream>>>(hist, bucket_base);
    radix_scatter<<<dim3(SB), blk, 0, stream>>>(src, dst, hist, tmp, E, epb, nbuk);
    radix_build<<<dim3(nbuk), blk, 0, stream>>>(tmp, bucket_base, csr_src, rowptr,
                                                dinv, rdinv, N);

    // ---- layer 1 ----
    prescale<<<gPre, blk, 0, stream>>>(feat, dinv, Ya, (int)(N * 16));
    spmm_m1<<<gWave, blk, 0, stream>>>(Ya, rowptr, csr_src, dinv, Yb, N);
    spmm_m2<<<gWave, blk, 0, stream>>>(Yb, rowptr, csr_src, dinv, feat, X2b, N);
    gemm_cheb<64><<<gGemm, blk, 0, stream>>>(feat, Yb, X2b, rdinv, W1, b1, H,
                                             dinv, Ya, N, 1);

    // ---- layer 2 ----
    spmm_m1<<<gWave, blk, 0, stream>>>(Ya, rowptr, csr_src, dinv, Yb, N);
    spmm_m2<<<gWave, blk, 0, stream>>>(Yb, rowptr, csr_src, dinv, H, X2b, N);
    gemm_cheb<32><<<gGemm, blk, 0, stream>>>(H, Yb, X2b, rdinv, W2, b2, out,
                                             dinv, nullptr, N, 0);
}

// Round 13
// 377.793 us; speedup vs baseline: 1.1561x; 1.1514x over previous
//
#include <hip/hip_runtime.h>

#define NF 64        // IN_F == HID_F == 64
#define BKSH 9       // bucket = dst >> 9 (512 nodes/bucket)
#define BKN 512      // nodes per bucket
#define SB 256       // superblocks (edge partitions)

typedef unsigned short u16;
typedef __attribute__((ext_vector_type(8))) short bf16x8;
typedef __attribute__((ext_vector_type(4))) float f32x4;

__device__ __forceinline__ float bf2f(unsigned h) {
    return __uint_as_float(h << 16);
}
__device__ __forceinline__ u16 f2bf(float x) {   // round-to-nearest-even
    unsigned u = __float_as_uint(x);
    return (u16)((u + 0x7FFFu + ((u >> 16) & 1u)) >> 16);
}

// ============ CSR build: two-phase radix partition (round-10 proven) ============

__launch_bounds__(256)
__global__ void radix_count(const int* __restrict__ dst, int* __restrict__ hist,
                            int* __restrict__ bucket_total, int E, int epb, int nbuk) {
    __shared__ int bins[BKN];
    int tid = threadIdx.x, sb = blockIdx.x;
    for (int i = tid; i < nbuk; i += 256) bins[i] = 0;
    __syncthreads();
    int base = sb * epb;
    int end = min(base + epb, E);
    for (int e = base + tid; e < end; e += 256)
        atomicAdd(&bins[dst[e] >> BKSH], 1);
    __syncthreads();
    for (int i = tid; i < nbuk; i += 256) {
        int c = bins[i];
        hist[i * SB + sb] = c;
        if (c) atomicAdd(&bucket_total[i], c);
    }
}

__global__ void bucket_scan(const int* __restrict__ bucket_total, int* __restrict__ bucket_base,
                            int* __restrict__ rowptr, int nbuk, int E, int N) {
    __shared__ int s[256];
    int tid = threadIdx.x;
    int v = (tid < nbuk) ? bucket_total[tid] : 0;
    s[tid] = v; __syncthreads();
    for (int off = 1; off < 256; off <<= 1) {
        int t = (tid >= off) ? s[tid - off] : 0;
        __syncthreads();
        s[tid] += t;
        __syncthreads();
    }
    if (tid <= nbuk) bucket_base[tid] = (tid < nbuk) ? (s[tid] - v) : E;
    if (tid == 0) rowptr[N] = E;
}

__global__ void hist_scan(int* __restrict__ hist, const int* __restrict__ bucket_base) {
    __shared__ int s[256];
    int b = blockIdx.x, tid = threadIdx.x;
    int v = hist[b * SB + tid];
    s[tid] = v; __syncthreads();
    for (int off = 1; off < 256; off <<= 1) {
        int t = (tid >= off) ? s[tid - off] : 0;
        __syncthreads();
        s[tid] += t;
        __syncthreads();
    }
    hist[b * SB + tid] = bucket_base[b] + s[tid] - v;
}

__launch_bounds__(256)
__global__ void radix_scatter(const int* __restrict__ src, const int* __restrict__ dst,
                              const int* __restrict__ hist, int* __restrict__ tmp,
                              int E, int epb, int nbuk) {
    __shared__ int cur[BKN];
    int tid = threadIdx.x, sb = blockIdx.x;
    for (int i = tid; i < nbuk; i += 256) cur[i] = hist[i * SB + sb];
    __syncthreads();
    int base = sb * epb;
    int end = min(base + epb, E);
    for (int e = base + tid; e < end; e += 256) {
        int d = dst[e];
        int b = d >> BKSH;
        int pos = atomicAdd(&cur[b], 1);
        tmp[pos] = ((d & (BKN - 1)) << 17) | src[e];
    }
}

__launch_bounds__(256)
__global__ void radix_build(const int* __restrict__ tmp, const int* __restrict__ bucket_base,
                            int* __restrict__ csr_src, int* __restrict__ rowptr,
                            float* __restrict__ dinv, int N) {
    __shared__ int cnt[BKN], excl[BKN], cur[BKN];
    __shared__ int s[256];
    int b = blockIdx.x, tid = threadIdx.x;
    int beg = bucket_base[b], end = bucket_base[b + 1];
    cnt[tid] = 0; cnt[tid + 256] = 0;
    __syncthreads();
    for (int e = beg + tid; e < end; e += 256)
        atomicAdd(&cnt[(tmp[e] >> 17) & (BKN - 1)], 1);
    __syncthreads();
    int c0 = cnt[2 * tid], c1 = cnt[2 * tid + 1];
    int v = c0 + c1;
    s[tid] = v; __syncthreads();
    for (int off = 1; off < 256; off <<= 1) {
        int t = (tid >= off) ? s[tid - off] : 0;
        __syncthreads();
        s[tid] += t;
        __syncthreads();
    }
    int base2 = s[tid] - v;
    excl[2 * tid] = base2;
    excl[2 * tid + 1] = base2 + c0;
    cur[2 * tid] = 0; cur[2 * tid + 1] = 0;
    int node0 = b << BKSH;
    int n0 = node0 + 2 * tid, n1 = n0 + 1;
    if (n0 < N) { rowptr[n0] = beg + base2;      dinv[n0] = rsqrtf(fmaxf((float)c0, 1.0f)); }
    if (n1 < N) { rowptr[n1] = beg + base2 + c0; dinv[n1] = rsqrtf(fmaxf((float)c1, 1.0f)); }
    __syncthreads();
    for (int e = beg + tid; e < end; e += 256) {
        int vv = tmp[e];
        int dlow = (vv >> 17) & (BKN - 1);
        int pos = excl[dlow] + atomicAdd(&cur[dlow], 1);
        csr_src[beg + pos] = vv & 0x1FFFF;
    }
}

// ============ W transpose+convert: Wt[c][k] = bf16(W[k][c]) ============
__global__ void wconv(const float* __restrict__ W, u16* __restrict__ Wt,
                      int K, int OUTF, int total) {
    int i = blockIdx.x * blockDim.x + threadIdx.x;
    if (i < total) {
        int k = i / OUTF, c = i - k * OUTF;
        Wt[(size_t)c * K + k] = f2bf(W[i]);
    }
}

// ============ prescale: Ya = bf16(X*dinv), Fb = bf16(X) ============
__global__ void prescale(const float* __restrict__ X, const float* __restrict__ dinv,
                         u16* __restrict__ Ya, u16* __restrict__ Fb, int total4) {
    int i = blockIdx.x * blockDim.x + threadIdx.x;
    if (i < total4) {
        int node = i >> 4;
        float dn = dinv[node];
        float4 v = ((const float4*)X)[i];
        ushort4 ys, yu;
        ys.x = f2bf(v.x * dn); ys.y = f2bf(v.y * dn);
        ys.z = f2bf(v.z * dn); ys.w = f2bf(v.w * dn);
        yu.x = f2bf(v.x); yu.y = f2bf(v.y); yu.z = f2bf(v.z); yu.w = f2bf(v.w);
        ((ushort4*)Ya)[i] = ys;
        ((ushort4*)Fb)[i] = yu;
    }
}

// ============ SpMM gathers: wave/node, 16 edges in flight, bf16 rows ============
#define SPMM_HEAD \
    int node = (blockIdx.x * blockDim.x + threadIdx.x) >> 6; \
    if (node >= n) return; \
    int lane = threadIdx.x & 63; \
    int g = lane >> 3; \
    int fl = (lane & 7) << 3; \
    int beg = rowptr[node], end = rowptr[node + 1]; \
    float acc[8], acc2[8]; \
    _Pragma("unroll") for (int j = 0; j < 8; ++j) { acc[j] = 0.f; acc2[j] = 0.f; } \
    int e0 = beg; \
    for (; e0 + 16 <= end; e0 += 16) { \
        int sA = csr_src[e0 + g]; \
        int sB = csr_src[e0 + 8 + g]; \
        uint4 uA = *(const uint4*)(Y + (size_t)sA * NF + fl); \
        uint4 uB = *(const uint4*)(Y + (size_t)sB * NF + fl); \
        acc[0] += bf2f(uA.x & 0xFFFFu); acc[1] += bf2f(uA.x >> 16); \
        acc[2] += bf2f(uA.y & 0xFFFFu); acc[3] += bf2f(uA.y >> 16); \
        acc[4] += bf2f(uA.z & 0xFFFFu); acc[5] += bf2f(uA.z >> 16); \
        acc[6] += bf2f(uA.w & 0xFFFFu); acc[7] += bf2f(uA.w >> 16); \
        acc2[0] += bf2f(uB.x & 0xFFFFu); acc2[1] += bf2f(uB.x >> 16); \
        acc2[2] += bf2f(uB.y & 0xFFFFu); acc2[3] += bf2f(uB.y >> 16); \
        acc2[4] += bf2f(uB.z & 0xFFFFu); acc2[5] += bf2f(uB.z >> 16); \
        acc2[6] += bf2f(uB.w & 0xFFFFu); acc2[7] += bf2f(uB.w >> 16); \
    } \
    for (; e0 < end; e0 += 8) { \
        int eg = e0 + g; \
        if (eg < end) { \
            int s = csr_src[eg]; \
            uint4 u = *(const uint4*)(Y + (size_t)s * NF + fl); \
            acc[0] += bf2f(u.x & 0xFFFFu); acc[1] += bf2f(u.x >> 16); \
            acc[2] += bf2f(u.y & 0xFFFFu); acc[3] += bf2f(u.y >> 16); \
            acc[4] += bf2f(u.z & 0xFFFFu); acc[5] += bf2f(u.z >> 16); \
            acc[6] += bf2f(u.w & 0xFFFFu); acc[7] += bf2f(u.w >> 16); \
        } \
    } \
    _Pragma("unroll") for (int j = 0; j < 8; ++j) acc[j] += acc2[j]; \
    _Pragma("unroll") for (int m = 8; m <= 32; m <<= 1) { \
        _Pragma("unroll") for (int j = 0; j < 8; ++j) acc[j] += __shfl_xor(acc[j], m, 64); \
    }

// mode 1: X1b = bf16(-acc*dinv)  (gemm operand),  Yout = bf16(-acc*dinv^2)  (next gather)
__launch_bounds__(256)
__global__ void spmm_m1(const u16* __restrict__ Y, const int* __restrict__ rowptr,
                        const int* __restrict__ csr_src, const float* __restrict__ dinv,
                        u16* __restrict__ Yout, u16* __restrict__ X1b, int n) {
    SPMM_HEAD
    if (g == 0) {
        float dn = dinv[node];
        float r[8];
#pragma unroll
        for (int j = 0; j < 8; ++j) r[j] = -acc[j] * dn;
        uint4 ub, uy;
        ub.x = (unsigned)f2bf(r[0]) | ((unsigned)f2bf(r[1]) << 16);
        ub.y = (unsigned)f2bf(r[2]) | ((unsigned)f2bf(r[3]) << 16);
        ub.z = (unsigned)f2bf(r[4]) | ((unsigned)f2bf(r[5]) << 16);
        ub.w = (unsigned)f2bf(r[6]) | ((unsigned)f2bf(r[7]) << 16);
        uy.x = (unsigned)f2bf(r[0] * dn) | ((unsigned)f2bf(r[1] * dn) << 16);
        uy.y = (unsigned)f2bf(r[2] * dn) | ((unsigned)f2bf(r[3] * dn) << 16);
        uy.z = (unsigned)f2bf(r[4] * dn) | ((unsigned)f2bf(r[5] * dn) << 16);
        uy.w = (unsigned)f2bf(r[6] * dn) | ((unsigned)f2bf(r[7] * dn) << 16);
        *(uint4*)(X1b + (size_t)node * NF + fl) = ub;
        *(uint4*)(Yout + (size_t)node * NF + fl) = uy;
    }
}

// mode 2: X2b = bf16(-2*acc*dinv - Xprev),  Xprev is bf16
__launch_bounds__(256)
__global__ void spmm_m2(const u16* __restrict__ Y, const int* __restrict__ rowptr,
                        const int* __restrict__ csr_src, const float* __restrict__ dinv,
                        const u16* __restrict__ Xprev, u16* __restrict__ X2b, int n) {
    SPMM_HEAD
    if (g == 0) {
        float dn = dinv[node];
        uint4 up = *(const uint4*)(Xprev + (size_t)node * NF + fl);
        float xp[8];
        xp[0] = bf2f(up.x & 0xFFFFu); xp[1] = bf2f(up.x >> 16);
        xp[2] = bf2f(up.y & 0xFFFFu); xp[3] = bf2f(up.y >> 16);
        xp[4] = bf2f(up.z & 0xFFFFu); xp[5] = bf2f(up.z >> 16);
        xp[6] = bf2f(up.w & 0xFFFFu); xp[7] = bf2f(up.w >> 16);
        float r[8];
#pragma unroll
        for (int j = 0; j < 8; ++j) r[j] = -2.f * acc[j] * dn - xp[j];
        uint4 uy;
        uy.x = (unsigned)f2bf(r[0]) | ((unsigned)f2bf(r[1]) << 16);
        uy.y = (unsigned)f2bf(r[2]) | ((unsigned)f2bf(r[3]) << 16);
        uy.z = (unsigned)f2bf(r[4]) | ((unsigned)f2bf(r[5]) << 16);
        uy.w = (unsigned)f2bf(r[6]) | ((unsigned)f2bf(r[7]) << 16);
        *(uint4*)(X2b + (size_t)node * NF + fl) = uy;
    }
}

// ============ GEMM v6 (MFMA): C[N x OUTF] = [X0b|X1b|X2b] @ W + b ============
// Wave = 16 nodes; block = 4 waves = 64 nodes. A[m=lane&15][k=q*8+j] (m120-verified),
// B symmetric via Wt[c][k] (contiguous k), D: col=lane&15, row=q*4+reg (m89-verified).
// No LDS. Layer1 (OUTF=64): writes Hb=bf16(H), Ya=bf16(H*dinv). Layer2: fp32 out.
template <int OUTF>
__launch_bounds__(256)
__global__ void gemm_mfma(const u16* __restrict__ X0b, const u16* __restrict__ X1b,
                          const u16* __restrict__ X2b, const u16* __restrict__ Wt,
                          const float* __restrict__ bias, const float* __restrict__ dinv,
                          float* __restrict__ outp, u16* __restrict__ Ya,
                          u16* __restrict__ Hb, int n, int do_relu) {
    constexpr int NT = OUTF / 16;   // 4 or 2 N-tiles
    const int wave = threadIdx.x >> 6;
    const int lane = threadIdx.x & 63;
    const int node0 = blockIdx.x * 64 + wave * 16;
    const int m = lane & 15;
    const int q = lane >> 4;
    const int arow = min(node0 + m, n - 1);   // OOB rows only corrupt unstored D rows

    union U8 { uint4 u; bf16x8 v; };

    f32x4 acc[NT];
#pragma unroll
    for (int t = 0; t < NT; ++t) acc[t] = (f32x4){0.f, 0.f, 0.f, 0.f};

    const u16* Xs[3] = {X0b, X1b, X2b};
#pragma unroll
    for (int p = 0; p < 3; ++p) {
        const u16* __restrict__ Xc = Xs[p];
#pragma unroll
        for (int h = 0; h < 2; ++h) {
            U8 a;
            a.u = *(const uint4*)(Xc + (size_t)arow * 64 + h * 32 + q * 8);
#pragma unroll
            for (int t = 0; t < NT; ++t) {
                U8 b;
                b.u = *(const uint4*)(Wt + (size_t)(t * 16 + m) * 192 + p * 64 + h * 32 + q * 8);
                acc[t] = __builtin_amdgcn_mfma_f32_16x16x32_bf16(a.v, b.v, acc[t], 0, 0, 0);
            }
        }
    }

    // epilogue: lane holds D[row=node0+q*4+r][col=t*16+m]
    float dv[4];
#pragma unroll
    for (int r = 0; r < 4; ++r) {
        int row = node0 + q * 4 + r;
        dv[r] = (OUTF == 64 && row < n) ? dinv[row] : 0.f;
    }
#pragma unroll
    for (int t = 0; t < NT; ++t) {
        int col = t * 16 + m;
        float bv = bias[col];
#pragma unroll
        for (int r = 0; r < 4; ++r) {
            int row = node0 + q * 4 + r;
            if (row < n) {
                float v = acc[t][r] + bv;
                if (do_relu) v = fmaxf(v, 0.f);
                if (OUTF == 64) {
                    Hb[(size_t)row * 64 + col] = f2bf(v);
                    Ya[(size_t)row * 64 + col] = f2bf(v * dv[r]);
                } else {
                    outp[(size_t)row * 32 + col] = v;
                }
            }
        }
    }
}

extern "C" void kernel_launch(void* const* d_in, const int* in_sizes, int n_in,
                              void* d_out, int out_size, void* d_ws, size_t ws_size,
                              hipStream_t stream) {
    const float* feat = (const float*)d_in[0];
    const int*   src  = (const int*)d_in[1];
    const int*   dst  = (const int*)d_in[2];
    const float* W1   = (const float*)d_in[3];
    const float* b1   = (const float*)d_in[4];
    const float* W2   = (const float*)d_in[5];
    const float* b2   = (const float*)d_in[6];
    float* out = (float*)d_out;

    const int N = in_sizes[0] / NF;   // 100000
    const int E = in_sizes[1];        // 1600000
    const size_t NFtot = (size_t)N * NF;
    const int nbuk = (N + BKN - 1) >> BKSH;   // 196
    const int epb = (E + SB - 1) / SB;        // 6250

    // workspace layout (16B-aligned chunks)
    char* p = (char*)d_ws;
    int* hist         = (int*)p;   p += (size_t)BKN * SB * 4;
    int* bucket_total = (int*)p;   p += (BKN + 16) * 4;
    int* bucket_base  = (int*)p;   p += (BKN + 16) * 4;
    int* rowptr       = (int*)p;   p += ((size_t)N + 16) * 4;
    int* csr_src      = (int*)p;   p += (size_t)E * 4;
    float* dinv       = (float*)p; p += ((size_t)N + 16) * 4;
    u16* Wt1          = (u16*)p;   p += 192 * 64 * 2;
    u16* Wt2          = (u16*)p;   p += 192 * 32 * 2;
    u16* Ya           = (u16*)p;   p += NFtot * 2;   // bf16(X0*dinv) gather table
    u16* Yb           = (u16*)p;   p += NFtot * 2;   // bf16(X1*dinv^2) gather table
    u16* X1b          = (u16*)p;   p += NFtot * 2;   // bf16(X1) gemm operand
    u16* X2b          = (u16*)p;   p += NFtot * 2;   // bf16(X2) gemm operand
    u16* Fb           = (u16*)p;   p += NFtot * 2;   // bf16(feat)
    u16* Hb           = (u16*)p;   p += NFtot * 2;   // bf16(H)
    int* tmp = (int*)Ya;           // alias; consumed before prescale writes Ya

    const int TB = 256;
    dim3 blk(TB);
    dim3 gWave(((size_t)N * 64 + TB - 1) / TB);
    dim3 gPre(((size_t)N * 16 + TB - 1) / TB);
    dim3 gGemm((N + 63) / 64);

    // ---- CSR build (radix partition) ----
    hipMemsetAsync(bucket_total, 0, (size_t)(BKN + 1) * sizeof(int), stream);
    radix_count<<<dim3(SB), blk, 0, stream>>>(dst, hist, bucket_total, E, epb, nbuk);
    bucket_scan<<<1, blk, 0, stream>>>(bucket_total, bucket_base, rowptr, nbuk, E, N);
    hist_scan<<<dim3(nbuk), blk, 0, stream>>>(hist, bucket_base);
    radix_scatter<<<dim3(SB), blk, 0, stream>>>(src, dst, hist, tmp, E, epb, nbuk);
    radix_build<<<dim3(nbuk), blk, 0, stream>>>(tmp, bucket_base, csr_src, rowptr, dinv, N);

    // ---- weights -> bf16 transposed ----
    wconv<<<dim3((192 * 64 + TB - 1) / TB), blk, 0, stream>>>(W1, Wt1, 192, 64, 192 * 64);
    wconv<<<dim3((192 * 32 + TB - 1) / TB), blk, 0, stream>>>(W2, Wt2, 192, 32, 192 * 32);

    // ---- layer 1 ----
    prescale<<<gPre, blk, 0, stream>>>(feat, dinv, Ya, Fb, (int)(N * 16));
    spmm_m1<<<gWave, blk, 0, stream>>>(Ya, rowptr, csr_src, dinv, Yb, X1b, N);
    spmm_m2<<<gWave, blk, 0, stream>>>(Yb, rowptr, csr_src, dinv, Fb, X2b, N);
    gemm_mfma<64><<<gGemm, blk, 0, stream>>>(Fb, X1b, X2b, Wt1, b1, dinv,
                                             nullptr, Ya, Hb, N, 1);

    // ---- layer 2 ----
    spmm_m1<<<gWave, blk, 0, stream>>>(Ya, rowptr, csr_src, dinv, Yb, X1b, N);
    spmm_m2<<<gWave, blk, 0, stream>>>(Yb, rowptr, csr_src, dinv, Hb, X2b, N);
    gemm_mfma<32><<<gGemm, blk, 0, stream>>>(Hb, X1b, X2b, Wt2, b2, dinv,
                                             out, nullptr, nullptr, N, 0);
}